// Round 3
// baseline (266.649 us; speedup 1.0000x reference)
//
#include <hip/hip_runtime.h>
#include <math.h>

// Problem constants
#define BHN     55392          // B*H*N = 8*12*577 (token count)
#define NTOK    577
#define HD      64
#define EPS_F   1e-6f
#define TOTAL_ELEMS 31961184   // BHN * 577
#define TOTAL_VEC   7990296    // TOTAL_ELEMS / 4

// ---------------------------------------------------------------------------
// Kernel A v3: per-token sigma MLP -> folded quadratic-form coefficients.
// coef[tok] = { a, b, c, pack }, w = a*dx^2 + b*dx*dy + c*dy^2.
// v3: W1 read with WAVE-UNIFORM addresses straight from global -> compiler
// emits s_load (constant cache, scalar pipe). No LDS at all: frees the
// LDS pipe that serialized v2 (1024 ds_read_b128 x 12cyc/wave). Rolled
// k-loop keeps the body I-cache resident. FMA floor: 4096 fma x 2cyc/wave.
// ---------------------------------------------------------------------------
__global__ __launch_bounds__(256) void sigma_coef_kernel(
    const float* __restrict__ q,  const float* __restrict__ W1,
    const float* __restrict__ b1, const float* __restrict__ W2,
    const float* __restrict__ b2, float4* __restrict__ coef)
{
    const int tok = blockIdx.x * 256 + threadIdx.x;
    if (tok >= BHN) return;

    float h[HD];
    #pragma unroll
    for (int t = 0; t < HD; ++t) h[t] = 0.0f;

    const float4* w1_4 = (const float4*)W1;      // uniform base
    const float4* q4   = (const float4*)(q + (size_t)tok * HD);
    float4 qv = q4[0];
    #pragma unroll 1
    for (int kk = 0; kk < 16; ++kk) {
        const int kn = (kk < 15) ? (kk + 1) : 15;
        float4 qnext = q4[kn];                   // prefetch next q chunk
        float qk[4] = {qv.x, qv.y, qv.z, qv.w};
        #pragma unroll
        for (int d = 0; d < 4; ++d) {
            float qs = qk[d];
            const int base = (kk * 4 + d) * 16;  // uniform -> s_load_dwordx16
            #pragma unroll
            for (int t4 = 0; t4 < 16; ++t4) {
                float4 wv = w1_4[base + t4];
                h[4*t4+0] = fmaf(qs, wv.x, h[4*t4+0]);
                h[4*t4+1] = fmaf(qs, wv.y, h[4*t4+1]);
                h[4*t4+2] = fmaf(qs, wv.z, h[4*t4+2]);
                h[4*t4+3] = fmaf(qs, wv.w, h[4*t4+3]);
            }
        }
        qv = qnext;
    }

    // s = gelu(h + b1) @ W2 + b2.  erf via A&S 7.1.26 (|err| <= 1.5e-7),
    // branchless. W2/b1 addresses uniform -> scalar loads.
    float s0 = b2[0], s1 = b2[1], s2 = b2[2];
    #pragma unroll
    for (int t = 0; t < HD; ++t) {
        float x = h[t] + b1[t];
        float z = x * 0.70710678118654752f;
        float az = fabsf(z);
        float k = __builtin_amdgcn_rcpf(fmaf(0.3275911f, az, 1.0f));
        float poly = k * (0.254829592f + k * (-0.284496736f +
                     k * (1.421413741f + k * (-1.453152027f +
                     k * 1.061405429f))));
        float om = poly * __expf(-z * z);        // 1 - erf(|z|)
        float erfz = copysignf(1.0f - om, z);
        float g = 0.5f * x * (1.0f + erfz);
        s0 = fmaf(g, W2[t*3 + 0], s0);
        s1 = fmaf(g, W2[t*3 + 1], s1);
        s2 = fmaf(g, W2[t*3 + 2], s2);
    }

    float sx = fmaxf(s0, 0.0f) + 1.0f;
    float sy = fmaxf(s1, 0.0f) + 1.0f;
    // tanh(x) = (e^2x - 1)/(e^2x + 1); s2 is O(0.02), no overflow
    float ex = __expf(2.0f * s2);
    float rho = 0.99f * ((ex - 1.0f) * __builtin_amdgcn_rcpf(ex + 1.0f));
    float sxx = sx * sx, syy = sy * sy;
    float sxy = rho * sx * sy;
    float det = sxx * syy - sxy * sxy;           // >= 0.0199
    float inv_det = 1.0f / det;

    float a = -0.5f * syy * inv_det;
    float b =  sxy * inv_det;
    float c = -0.5f * sxx * inv_det;

    int i = tok % NTOK;
    float pack;
    if (i == 0) { a = 0.0f; b = 0.0f; c = 0.0f; pack = 0.0f; }
    else {
        int ip = i - 1;
        int ri = ip / 24;
        int ci = ip - ri * 24;
        pack = (float)(ri * 32 + ci);
    }
    coef[tok] = make_float4(a, b, c, pack);
}

// ---------------------------------------------------------------------------
// Kernel B v3: elementwise mask. rowmax(kernel)==1 structurally, so
// probs = clip(exp(w), eps, 1-eps).
// v3 key identity: sigmoid((logits+noise)/0.1) = 1 / (1 + r^10) with
// r = (1-p)(1-u) / (p*u).  r^10 by repeated squaring (4 muls) replaces
// 2 logs + 1 exp.  r^10 overflow->inf->mask=0, underflow->0->mask=1:
// both are the correct limits. Remaining trans-pipe: expf(w) + 2 rcp.
// ---------------------------------------------------------------------------
__global__ __launch_bounds__(256) void mask_kernel(
    const float4* __restrict__ u4, const float4* __restrict__ coef,
    float4* __restrict__ out4)
{
    int vid = blockIdx.x * 256 + threadIdx.x;
    if (vid >= TOTAL_VEC) return;

    int e0 = vid * 4;
    unsigned row0 = (unsigned)e0 / 577u;             // magic-div
    int j0 = e0 - (int)row0 * 577;

    // at most one row crossing within 4 elems; last vec has j0=573 -> no
    // crossing, so row1 < BHN always.
    unsigned row1 = row0 + ((j0 + 3 >= 577) ? 1u : 0u);
    float4 cf0 = coef[row0];                         // independent loads,
    float4 cf1 = coef[row1];                         // all 3 in flight
    float4 uu = u4[vid];

    float um[4] = {uu.x, uu.y, uu.z, uu.w};
    float res[4];

    #pragma unroll
    for (int m = 0; m < 4; ++m) {
        int j = j0 + m;
        bool crossed = (j >= 577);
        if (crossed) j -= 577;
        float4 cf;
        cf.x = crossed ? cf1.x : cf0.x;
        cf.y = crossed ? cf1.y : cf0.y;
        cf.z = crossed ? cf1.z : cf0.z;
        cf.w = crossed ? cf1.w : cf0.w;
        int rc = (int)cf.w;

        float dx = 0.0f, dy = 0.0f;
        if (j > 0) {
            unsigned jj = (unsigned)(j - 1);
            unsigned rj = jj / 24u;                  // magic-div
            unsigned cj = jj - rj * 24u;
            dx = (float)((rc >> 5) - (int)rj);
            dy = (float)((rc & 31) - (int)cj);
        }

        // w = a*dx^2 + b*dx*dy + c*dy^2  (<= 0)
        float w = fmaf(fmaf(cf.x, dx, cf.y * dy), dx, cf.z * (dy * dy));

        float p = __expf(w);
        p = fminf(fmaxf(p, EPS_F), 1.0f - EPS_F);    // 1-p exact (Sterbenz)

        float uk  = um[m];
        float num = p * uk;                          // >= 1e-12
        float den = (1.0f - p) * (1.0f - uk);
        float r   = den * __builtin_amdgcn_rcpf(num);

        float r2  = r * r;
        float r4  = r2 * r2;
        float r5  = r4 * r;
        float r10 = r5 * r5;                         // inf/0 limits correct

        res[m] = __builtin_amdgcn_rcpf(1.0f + r10);
    }

    out4[vid] = make_float4(res[0], res[1], res[2], res[3]);
}

// ---------------------------------------------------------------------------
extern "C" void kernel_launch(void* const* d_in, const int* in_sizes, int n_in,
                              void* d_out, int out_size, void* d_ws, size_t ws_size,
                              hipStream_t stream) {
    const float* q  = (const float*)d_in[0];
    const float* W1 = (const float*)d_in[1];
    const float* b1 = (const float*)d_in[2];
    const float* W2 = (const float*)d_in[3];
    const float* b2 = (const float*)d_in[4];
    const float* u  = (const float*)d_in[5];
    // d_in[6] = dists: recomputed on the fly, not loaded.

    float4* coef = (float4*)d_ws;                    // 886 KB scratch

    sigma_coef_kernel<<<(BHN + 255) / 256, 256, 0, stream>>>(q, W1, b1, W2, b2, coef);
    mask_kernel<<<(TOTAL_VEC + 255) / 256, 256, 0, stream>>>(
        (const float4*)u, coef, (float4*)d_out);
}